// Round 2
// baseline (554.738 us; speedup 1.0000x reference)
//
#include <hip/hip_runtime.h>

#define IN_C 512
#define OUT_C 512
#define BATCH 16
#define NPX 4096   // 64*64

using bf16x8 = __attribute__((ext_vector_type(8))) __bf16;
using f32x4  = __attribute__((ext_vector_type(4))) float;

static constexpr float kConvScale = 0.014731391274719739f; // 1/sqrt(512*9)
static constexpr float kModScale  = 0.04419417382415922f;  // 1/sqrt(512)
static constexpr float kEps       = 1e-8f;

#define WT_TILE_BYTES (9 * 128 * 64)   // 73728 B per (ics, ot) weight tile

// ---------- 1) s[b][ic] = style[b,:] . mod_weight[ic,:] * MOD_SCALE + mod_bias[ic]
__global__ void style_k(const float* __restrict__ style, const float* __restrict__ mw,
                        const float* __restrict__ mb, float* __restrict__ s) {
  __shared__ float st[IN_C];
  const int b = blockIdx.x, t = threadIdx.x;   // 512 threads
  st[t] = style[b * IN_C + t];
  __syncthreads();
  const float4* row = (const float4*)(mw + (size_t)t * IN_C);
  float acc = 0.f;
  #pragma unroll 4
  for (int i = 0; i < IN_C / 4; i++) {
    float4 v = row[i];
    float4 u = *(const float4*)(st + i * 4);
    acc += v.x * u.x + v.y * u.y + v.z * u.z + v.w * u.w;
  }
  s[b * IN_C + t] = acc * kModScale + mb[t];
}

// ---------- 2) wsq[oc][ic] = sum_tap w^2 ; wsw = bf16 weights, tile-major + XOR-swizzled
// Tile (ics, ot): logical byte B = (tap*128 + oc_local)*64 + ic_local*2,
// stored at B ^ (((B>>7)&7)<<4).
__global__ void wprep_k(const float* __restrict__ w, float* __restrict__ wsq,
                        char* __restrict__ wsw) {
  const int idx = blockIdx.x * 256 + threadIdx.x;  // 262144 total
  const int ic = idx & (IN_C - 1), oc = idx >> 9;
  const int ot = oc >> 7, ocl = oc & 127, ics = ic >> 5, icl = ic & 31;
  char* tile = wsw + (size_t)(ics * 4 + ot) * WT_TILE_BYTES;
  const float* p = w + (size_t)(oc * IN_C + ic) * 9;
  float q = 0.f;
  #pragma unroll
  for (int t = 0; t < 9; t++) {
    float v = p[t];
    q += v * v;
    int B = ((t * 128 + ocl) << 6) + icl * 2;
    int Bsw = B ^ (((B >> 7) & 7) << 4);
    *(__bf16*)(tile + Bsw) = (__bf16)v;
  }
  wsq[oc * IN_C + ic] = q;
}

// ---------- 3) dscale[b][oc] = CONV_SCALE * rsqrt(CONV_SCALE^2 * sum_ic s^2*wsq + eps)
__global__ void demod_k(const float* __restrict__ s, const float* __restrict__ wsq,
                        float* __restrict__ dsc) {
  __shared__ float s2[IN_C];
  const int b = blockIdx.x, t = threadIdx.x;   // 512 threads
  float sv = s[b * IN_C + t];
  s2[t] = sv * sv;
  __syncthreads();
  const float4* row = (const float4*)(wsq + (size_t)t * IN_C);
  float acc = 0.f;
  #pragma unroll 4
  for (int i = 0; i < IN_C / 4; i++) {
    float4 v = row[i];
    float4 u = *(const float4*)(s2 + i * 4);
    acc += v.x * u.x + v.y * u.y + v.z * u.z + v.w * u.w;
  }
  dsc[b * OUT_C + t] = kConvScale * rsqrtf(kConvScale * kConvScale * acc + kEps);
}

// ---------- 4) xmod[b][p][ic] = bf16(x[b][ic][p] * s[b][ic])   (NCHW -> NHWC transpose)
__global__ void modx_k(const float* __restrict__ x, const float* __restrict__ s,
                       __bf16* __restrict__ xm) {
  __shared__ __bf16 tile[64][73];
  const int t = threadIdx.x;                   // 256 threads
  const int bid = blockIdx.x;                  // 16 * 8 * 64
  const int ict = bid & 7, pt = (bid >> 3) & 63, b = bid >> 9;
  const int ic0 = ict * 64, p0 = pt * 64;
  #pragma unroll
  for (int it = 0; it < 16; it++) {
    int idx = it * 256 + t;
    int pl = idx & 63, icl = idx >> 6;
    int ic = ic0 + icl;
    float v = x[((size_t)b * IN_C + ic) * NPX + p0 + pl] * s[b * IN_C + ic];
    tile[icl][pl] = (__bf16)v;
  }
  __syncthreads();
  #pragma unroll
  for (int it = 0; it < 2; it++) {
    int idx = it * 256 + t;
    int icb = idx & 7, pl = idx >> 3;
    alignas(16) __bf16 tmp[8];
    #pragma unroll
    for (int j = 0; j < 8; j++) tmp[j] = tile[icb * 8 + j][pl];
    *(uint4*)(xm + ((size_t)b * NPX + p0 + pl) * IN_C + ic0 + icb * 8) = *(const uint4*)tmp;
  }
}

// ---------- 5) conv: block = 512 thr (8 waves), tile 128 oc x 512 px (8 rows)
// Round-0 (253 us) structure + ONE change: counted-vmcnt tap-group waits (T3/T4).
// The 9 glds per thread are tap-ordered (glds #t fills tap t's 8 KB region), so
// the old full drain (__syncthreads => vmcnt(0), ~4K cyc/step stall) is replaced by:
//   vmcnt(6)+bar -> taps 0-2 resident, compute; vmcnt(3)+bar -> taps 3-5;
//   vmcnt(0)+bar -> taps 6-8. Weight arrival overlaps tap compute.
// LOADX moved after the vmcnt(0) wait so its wave-nonuniform load count (edge
// blocks) never crosses a counted wait (consumed by WRITEX's compiler wait).
// Barrier (a) is a raw s_barrier: register deps already force all LDS reads
// consumed pre-barrier; nothing drains to 0 at step top.
// NO register/layout changes vs round 0 (round 1's rolling pipeline spilled:
// WRITE_SIZE 131->726 MB = scratch traffic; this version must stay at VGPR~116).
#define ICP 40   // input LDS: 32 ic + pad -> 80B row stride

#define SGB __builtin_amdgcn_sched_group_barrier
#define SGB_MIX() { SGB(0x100, 3, 0); SGB(0x8, 8, 0); SGB(0x100, 3, 0); SGB(0x8, 8, 0); \
                    SGB(0x100, 3, 0); SGB(0x8, 8, 0); SGB(0x100, 3, 0); SGB(0x8, 8, 0); }
#define SGB_MFMA() { SGB(0x8, 8, 0); SGB(0x8, 8, 0); SGB(0x8, 8, 0); SGB(0x8, 8, 0); }

#define WAITV(N) asm volatile("s_waitcnt vmcnt(" #N ")" ::: "memory")
#define WAITL()  asm volatile("s_waitcnt lgkmcnt(0)" ::: "memory")
#define SBAR()   { __builtin_amdgcn_sched_barrier(0); __builtin_amdgcn_s_barrier(); \
                   __builtin_amdgcn_sched_barrier(0); }

__global__ __launch_bounds__(512, 2)
void conv_k(const __bf16* __restrict__ xm, const char* __restrict__ wsw,
            const float* __restrict__ dsc, float* __restrict__ out) {
  __shared__ __align__(16) __bf16 xs[10][66][ICP];  // rows h0-1..h0+8, cols -1..64, 32 ic
  __shared__ uint4 wsb4[WT_TILE_BYTES / 16];        // swizzled weight tile (linear copy)
  char* wsb = (char*)wsb4;

  const int tid = threadIdx.x;
  const int lane = tid & 63;
  const int wv = tid >> 6;
  const int wm = wv >> 2, wn = wv & 3;       // 2 oc-halves x 4 px-quarters
  const int l15 = lane & 15, kb8 = lane >> 4;
  const int bid = blockIdx.x;
  const int pt = bid & 7, ot = (bid >> 3) & 3, b = bid >> 5;
  const int h0 = pt * 8, oc0 = ot * 128;

  // zero halo columns (cc = 0 and 65), all 10 rows; never overwritten
  if (tid < 80) {
    int ckb = tid & 3, side = (tid >> 2) & 1, r = tid >> 3;
    uint4 z = {0, 0, 0, 0};
    *(uint4*)(&xs[r][side * 65][ckb * 8]) = z;
  }

  // input staging geometry: idx = it*512 + tid -> ckb, c, r
  const int s_ckb = tid & 3, s_c = (tid >> 2) & 63, s_rb = tid >> 8;
  const __bf16* xbase = xm + (size_t)b * NPX * IN_C + s_c * IN_C + s_ckb * 8;

  uint4 ld[5];
  #define LOADX(ICS)                                                          \
    {                                                                         \
      _Pragma("unroll")                                                       \
      for (int it = 0; it < 5; it++) {                                        \
        int r = it * 2 + s_rb;                                                \
        int h = h0 + r - 1;                                                   \
        uint4 v = {0, 0, 0, 0};                                               \
        if ((unsigned)h < 64u)                                                \
          v = *(const uint4*)(xbase + (size_t)h * 64 * IN_C + (ICS) * 32);    \
        ld[it] = v;                                                           \
      }                                                                       \
    }
  #define WRITEX()                                                            \
    {                                                                         \
      _Pragma("unroll")                                                       \
      for (int it = 0; it < 5; it++) {                                        \
        int r = it * 2 + s_rb;                                                \
        *(uint4*)(&xs[r][s_c + 1][s_ckb * 8]) = ld[it];                       \
      }                                                                       \
    }
  // all-9-tap weight tile, zero-register staging (linear dest, source pre-swizzled)
  // glds #it covers tap it (8192 B each) -> per-wave vmcnt partitions by tap group.
  #define LOADW(ICS)                                                          \
    {                                                                         \
      const char* wt = wsw + (size_t)((ICS) * 4 + ot) * WT_TILE_BYTES;        \
      _Pragma("unroll")                                                       \
      for (int it = 0; it < 9; it++) {                                        \
        int off = (it * 512 + tid) * 16;                                      \
        __builtin_amdgcn_global_load_lds(                                     \
            (const __attribute__((address_space(1))) void*)(wt + off),        \
            (__attribute__((address_space(3))) void*)(wsb + off), 16, 0, 0);  \
      }                                                                       \
    }

  f32x4 acc[4][8];
  #pragma unroll
  for (int i = 0; i < 4; i++)
    #pragma unroll
    for (int j = 0; j < 8; j++) acc[i][j] = f32x4{0.f, 0.f, 0.f, 0.f};

  // swizzled weight read address: oc_local = wm*64 + fm*16 + l15 (fm adds fm*1024 B)
  const int ocr_base = wm * 64 + l15;
  const int swz = ((l15 >> 1) & 7) << 4;
  const int wrd_base = ((ocr_base << 6) + kb8 * 16) ^ swz;

  // tap-level fragment pipeline: load tap T's fragments into named buffers
  bf16x8 afA[4], bfA[8], afB[4], bfB[8];
  #define LOADT(T, AF, BF)                                                    \
    {                                                                         \
      _Pragma("unroll")                                                       \
      for (int fm = 0; fm < 4; fm++)                                          \
        AF[fm] = *(const bf16x8*)(wsb + ((T) * 8192 + fm * 1024 + wrd_base)); \
      _Pragma("unroll")                                                       \
      for (int fn = 0; fn < 8; fn++) {                                        \
        int px = wn * 128 + fn * 16 + l15;                                    \
        BF[fn] = *(const bf16x8*)(&xs[(px >> 6) + ((T) / 3)]                  \
                                     [(px & 63) + ((T) % 3)]                  \
                                     [kb8 * 8]);                              \
      }                                                                       \
    }
  #define MFMAT(AF, BF)                                                       \
    {                                                                         \
      _Pragma("unroll")                                                       \
      for (int fm = 0; fm < 4; fm++)                                          \
        _Pragma("unroll")                                                     \
        for (int fn = 0; fn < 8; fn++)                                        \
          acc[fm][fn] = __builtin_amdgcn_mfma_f32_16x16x32_bf16(              \
              AF[fm], BF[fn], acc[fm][fn], 0, 0, 0);                          \
    }

  LOADX(0)

  for (int s = 0; s < 16; s++) {
    SBAR();                                // (a) readers of previous step done (raw barrier)
    LOADW(s)                               // 9 glds, tap-ordered
    WRITEX()                               // input regs -> LDS (compiler waits ld loads)

    WAITV(6); WAITL(); SBAR();             // (b) taps 0-2 resident + xs visible
    LOADT(0, afA, bfA)
    LOADT(1, afB, bfB)
    MFMAT(afA, bfA)  SGB_MIX()             // t0
    LOADT(2, afA, bfA)
    MFMAT(afB, bfB)  SGB_MIX()             // t1 || load t2

    WAITV(3); SBAR();                      // (c) taps 3-5 resident
    LOADT(3, afB, bfB)
    MFMAT(afA, bfA)  SGB_MIX()             // t2 || load t3
    LOADT(4, afA, bfA)
    MFMAT(afB, bfB)  SGB_MIX()             // t3 || load t4
    LOADT(5, afB, bfB)
    MFMAT(afA, bfA)  SGB_MIX()             // t4 || load t5

    WAITV(0); SBAR();                      // (d) taps 6-8 resident
    LOADT(6, afA, bfA)
    if (s < 15) LOADX(s + 1)               // next-step input; overlaps taps 5-8
    MFMAT(afB, bfB)  SGB_MIX()             // t5 || load t6
    LOADT(7, afB, bfB)
    MFMAT(afA, bfA)  SGB_MIX()             // t6 || load t7
    LOADT(8, afA, bfA)
    MFMAT(afB, bfB)  SGB_MIX()             // t7 || load t8
    MFMAT(afA, bfA)  SGB_MFMA()            // t8
  }

  // epilogue: D row = oc (= kb8*4+j), col = px (= l15)
  #pragma unroll
  for (int fm = 0; fm < 4; fm++) {
    #pragma unroll
    for (int j = 0; j < 4; j++) {
      int oc = oc0 + wm * 64 + fm * 16 + kb8 * 4 + j;
      float dm = dsc[b * OUT_C + oc];
      float* orow = out + ((size_t)b * OUT_C + oc) * NPX + h0 * 64;
      #pragma unroll
      for (int fn = 0; fn < 8; fn++) {
        int px = wn * 128 + fn * 16 + l15;
        orow[px] = acc[fm][fn][j] * dm;
      }
    }
  }
}

extern "C" void kernel_launch(void* const* d_in, const int* in_sizes, int n_in,
                              void* d_out, int out_size, void* d_ws, size_t ws_size,
                              hipStream_t stream) {
  const float* input  = (const float*)d_in[0];
  const float* style  = (const float*)d_in[1];
  const float* weight = (const float*)d_in[2];
  const float* mod_w  = (const float*)d_in[3];
  const float* mod_b  = (const float*)d_in[4];
  float* out = (float*)d_out;

  char* p = (char*)d_ws;
  float* s    = (float*)p;  p += (size_t)BATCH * IN_C * 4;       // 32 KB
  float* dsc  = (float*)p;  p += (size_t)BATCH * OUT_C * 4;      // 32 KB
  float* wsq  = (float*)p;  p += (size_t)OUT_C * IN_C * 4;       // 1 MB
  char*  wsw  = p;          p += (size_t)16 * 4 * WT_TILE_BYTES; // 4.5 MB
  __bf16* xm  = (__bf16*)p;                                      // 64 MB

  style_k<<<BATCH, 512, 0, stream>>>(style, mod_w, mod_b, s);
  wprep_k<<<1024, 256, 0, stream>>>(weight, wsq, wsw);
  demod_k<<<BATCH, 512, 0, stream>>>(s, wsq, dsc);
  modx_k<<<BATCH * 8 * 64, 256, 0, stream>>>(input, s, xm);
  conv_k<<<BATCH * 4 * 8, 512, 0, stream>>>(xm, wsw, dsc, out);
}

// Round 3
// 415.596 us; speedup vs baseline: 1.3348x; 1.3348x over previous
//
#include <hip/hip_runtime.h>

#define IN_C 512
#define OUT_C 512
#define BATCH 16
#define NPX 4096   // 64*64

using bf16x8 = __attribute__((ext_vector_type(8))) __bf16;
using f32x4  = __attribute__((ext_vector_type(4))) float;

static constexpr float kConvScale = 0.014731391274719739f; // 1/sqrt(512*9)
static constexpr float kModScale  = 0.04419417382415922f;  // 1/sqrt(512)
static constexpr float kEps       = 1e-8f;

#define WT_TILE_BYTES (9 * 128 * 64)   // 73728 B per (ics, ot) weight tile

// ---------- 1) s[b][ic] = style[b,:] . mod_weight[ic,:] * MOD_SCALE + mod_bias[ic]
__global__ void style_k(const float* __restrict__ style, const float* __restrict__ mw,
                        const float* __restrict__ mb, float* __restrict__ s) {
  __shared__ float st[IN_C];
  const int b = blockIdx.x, t = threadIdx.x;   // 512 threads
  st[t] = style[b * IN_C + t];
  __syncthreads();
  const float4* row = (const float4*)(mw + (size_t)t * IN_C);
  float acc = 0.f;
  #pragma unroll 4
  for (int i = 0; i < IN_C / 4; i++) {
    float4 v = row[i];
    float4 u = *(const float4*)(st + i * 4);
    acc += v.x * u.x + v.y * u.y + v.z * u.z + v.w * u.w;
  }
  s[b * IN_C + t] = acc * kModScale + mb[t];
}

// ---------- 2) wsq[oc][ic] = sum_tap w^2 ; wsw = bf16 weights, tile-major + XOR-swizzled
// Tile (ics, ot): logical byte B = (tap*128 + oc_local)*64 + ic_local*2,
// stored at B ^ (((B>>7)&7)<<4).
__global__ void wprep_k(const float* __restrict__ w, float* __restrict__ wsq,
                        char* __restrict__ wsw) {
  const int idx = blockIdx.x * 256 + threadIdx.x;  // 262144 total
  const int ic = idx & (IN_C - 1), oc = idx >> 9;
  const int ot = oc >> 7, ocl = oc & 127, ics = ic >> 5, icl = ic & 31;
  char* tile = wsw + (size_t)(ics * 4 + ot) * WT_TILE_BYTES;
  const float* p = w + (size_t)(oc * IN_C + ic) * 9;
  float q = 0.f;
  #pragma unroll
  for (int t = 0; t < 9; t++) {
    float v = p[t];
    q += v * v;
    int B = ((t * 128 + ocl) << 6) + icl * 2;
    int Bsw = B ^ (((B >> 7) & 7) << 4);
    *(__bf16*)(tile + Bsw) = (__bf16)v;
  }
  wsq[oc * IN_C + ic] = q;
}

// ---------- 3) dscale[b][oc] = CONV_SCALE * rsqrt(CONV_SCALE^2 * sum_ic s^2*wsq + eps)
__global__ void demod_k(const float* __restrict__ s, const float* __restrict__ wsq,
                        float* __restrict__ dsc) {
  __shared__ float s2[IN_C];
  const int b = blockIdx.x, t = threadIdx.x;   // 512 threads
  float sv = s[b * IN_C + t];
  s2[t] = sv * sv;
  __syncthreads();
  const float4* row = (const float4*)(wsq + (size_t)t * IN_C);
  float acc = 0.f;
  #pragma unroll 4
  for (int i = 0; i < IN_C / 4; i++) {
    float4 v = row[i];
    float4 u = *(const float4*)(s2 + i * 4);
    acc += v.x * u.x + v.y * u.y + v.z * u.z + v.w * u.w;
  }
  dsc[b * OUT_C + t] = kConvScale * rsqrtf(kConvScale * kConvScale * acc + kEps);
}

// ---------- 4) xmod[b][p][ic] = bf16(x[b][ic][p] * s[b][ic])   (NCHW -> NHWC transpose)
__global__ void modx_k(const float* __restrict__ x, const float* __restrict__ s,
                       __bf16* __restrict__ xm) {
  __shared__ __bf16 tile[64][73];
  const int t = threadIdx.x;                   // 256 threads
  const int bid = blockIdx.x;                  // 16 * 8 * 64
  const int ict = bid & 7, pt = (bid >> 3) & 63, b = bid >> 9;
  const int ic0 = ict * 64, p0 = pt * 64;
  #pragma unroll
  for (int it = 0; it < 16; it++) {
    int idx = it * 256 + t;
    int pl = idx & 63, icl = idx >> 6;
    int ic = ic0 + icl;
    float v = x[((size_t)b * IN_C + ic) * NPX + p0 + pl] * s[b * IN_C + ic];
    tile[icl][pl] = (__bf16)v;
  }
  __syncthreads();
  #pragma unroll
  for (int it = 0; it < 2; it++) {
    int idx = it * 256 + t;
    int icb = idx & 7, pl = idx >> 3;
    alignas(16) __bf16 tmp[8];
    #pragma unroll
    for (int j = 0; j < 8; j++) tmp[j] = tile[icb * 8 + j][pl];
    *(uint4*)(xm + ((size_t)b * NPX + p0 + pl) * IN_C + ic0 + icb * 8) = *(const uint4*)tmp;
  }
}

// ---------- 5) conv: block = 512 thr (8 waves), tile 128 oc x 512 px (8 rows)
// Round-0 (253 us) structure + ONE change: weight A-fragments are read DIRECTLY
// from the pre-swizzled global tile (coalesced 1 KB/instr; the 4 same-wm waves
// hit the same lines in L1), instead of glds-staged into LDS.
// Deletes per CU-step: 288 weight ds_read_b128 (~3.5K cyc of the ~14K LDS wall),
// the 73.7 KB glds burst + its vmcnt(0) barrier drain, and the glds LDS-write BW.
// Weight vmem (295 KB/CU-step, L1-deduped to ~74 KB L2 traffic) rides the separate
// vmem pipe under the remaining ~9K-cyc LDS wall.
// Swizzle identity: for A-addresses, (B>>7)&7 == (l15>>1)&7, so the existing
// wrd_base math reads the swizzled global tile correctly.
// NO asm barriers / sched_barrier(0) (rounds 1-2 proved they spill: VGPR 128 +
// WRITE_SIZE 726-899 MB scratch). afA/afB WAR deps throttle VMEM hoisting.
#define ICP 40   // input LDS: 32 ic + pad -> 80B row stride

#define SGB __builtin_amdgcn_sched_group_barrier
// per tap (pipelined 1 ahead): 4 VMEM_READ (A, global) + 8 DS_READ (B, LDS) + 32 MFMA
#define SGB_MIX() { SGB(0x20, 1, 0); SGB(0x100, 2, 0); SGB(0x8, 8, 0); \
                    SGB(0x20, 1, 0); SGB(0x100, 2, 0); SGB(0x8, 8, 0); \
                    SGB(0x20, 1, 0); SGB(0x100, 2, 0); SGB(0x8, 8, 0); \
                    SGB(0x20, 1, 0); SGB(0x100, 2, 0); SGB(0x8, 8, 0); }
#define SGB_MFMA() { SGB(0x8, 8, 0); SGB(0x8, 8, 0); SGB(0x8, 8, 0); SGB(0x8, 8, 0); }

__global__ __launch_bounds__(512, 2)
void conv_k(const __bf16* __restrict__ xm, const char* __restrict__ wsw,
            const float* __restrict__ dsc, float* __restrict__ out) {
  __shared__ __align__(16) __bf16 xs[10][66][ICP];  // rows h0-1..h0+8, cols -1..64, 32 ic

  const int tid = threadIdx.x;
  const int lane = tid & 63;
  const int wv = tid >> 6;
  const int wm = wv >> 2, wn = wv & 3;       // 2 oc-halves x 4 px-quarters
  const int l15 = lane & 15, kb8 = lane >> 4;
  const int bid = blockIdx.x;
  const int pt = bid & 7, ot = (bid >> 3) & 3, b = bid >> 5;
  const int h0 = pt * 8, oc0 = ot * 128;

  // zero halo columns (cc = 0 and 65), all 10 rows; never overwritten
  if (tid < 80) {
    int ckb = tid & 3, side = (tid >> 2) & 1, r = tid >> 3;
    uint4 z = {0, 0, 0, 0};
    *(uint4*)(&xs[r][side * 65][ckb * 8]) = z;
  }

  // input staging geometry: idx = it*512 + tid -> ckb, c, r
  const int s_ckb = tid & 3, s_c = (tid >> 2) & 63, s_rb = tid >> 8;
  const __bf16* xbase = xm + (size_t)b * NPX * IN_C + s_c * IN_C + s_ckb * 8;

  uint4 ld[5];
  #define LOADX(ICS)                                                          \
    {                                                                         \
      _Pragma("unroll")                                                       \
      for (int it = 0; it < 5; it++) {                                        \
        int r = it * 2 + s_rb;                                                \
        int h = h0 + r - 1;                                                   \
        uint4 v = {0, 0, 0, 0};                                               \
        if ((unsigned)h < 64u)                                                \
          v = *(const uint4*)(xbase + (size_t)h * 64 * IN_C + (ICS) * 32);    \
        ld[it] = v;                                                           \
      }                                                                       \
    }
  #define WRITEX()                                                            \
    {                                                                         \
      _Pragma("unroll")                                                       \
      for (int it = 0; it < 5; it++) {                                        \
        int r = it * 2 + s_rb;                                                \
        *(uint4*)(&xs[r][s_c + 1][s_ckb * 8]) = ld[it];                       \
      }                                                                       \
    }

  f32x4 acc[4][8];
  #pragma unroll
  for (int i = 0; i < 4; i++)
    #pragma unroll
    for (int j = 0; j < 8; j++) acc[i][j] = f32x4{0.f, 0.f, 0.f, 0.f};

  // swizzled weight read address: oc_local = wm*64 + fm*16 + l15 (fm adds fm*1024 B)
  const int ocr_base = wm * 64 + l15;
  const int swz = ((l15 >> 1) & 7) << 4;
  const int wrd_base = ((ocr_base << 6) + kb8 * 16) ^ swz;

  // tap-level fragment pipeline: load tap T's fragments into named buffers.
  // A from GLOBAL (swizzled tile, coalesced), B from LDS.
  bf16x8 afA[4], bfA[8], afB[4], bfB[8];
  #define LOADT(T, AF, BF)                                                    \
    {                                                                         \
      _Pragma("unroll")                                                       \
      for (int fm = 0; fm < 4; fm++)                                          \
        AF[fm] = *(const bf16x8*)(wtile + ((T) * 8192 + fm * 1024 + wrd_base)); \
      _Pragma("unroll")                                                       \
      for (int fn = 0; fn < 8; fn++) {                                        \
        int px = wn * 128 + fn * 16 + l15;                                    \
        BF[fn] = *(const bf16x8*)(&xs[(px >> 6) + ((T) / 3)]                  \
                                     [(px & 63) + ((T) % 3)]                  \
                                     [kb8 * 8]);                              \
      }                                                                       \
    }
  #define MFMAT(AF, BF)                                                       \
    {                                                                         \
      _Pragma("unroll")                                                       \
      for (int fm = 0; fm < 4; fm++)                                          \
        _Pragma("unroll")                                                     \
        for (int fn = 0; fn < 8; fn++)                                        \
          acc[fm][fn] = __builtin_amdgcn_mfma_f32_16x16x32_bf16(              \
              AF[fm], BF[fn], acc[fm][fn], 0, 0, 0);                          \
    }

  LOADX(0)

  for (int s = 0; s < 16; s++) {
    const char* wtile = wsw + (size_t)(s * 4 + ot) * WT_TILE_BYTES;
    __syncthreads();                       // (a) readers of previous step done
    WRITEX()                               // input regs -> LDS
    __syncthreads();                       // (b) xs visible
    if (s < 15) LOADX(s + 1)               // prefetch next input into regs

    LOADT(0, afA, bfA)
    LOADT(1, afB, bfB)
    MFMAT(afA, bfA)  SGB_MIX()             // t0 (overlaps t1 loads issued above)
    LOADT(2, afA, bfA)
    MFMAT(afB, bfB)  SGB_MIX()             // t1 || load t2
    LOADT(3, afB, bfB)
    MFMAT(afA, bfA)  SGB_MIX()             // t2 || load t3
    LOADT(4, afA, bfA)
    MFMAT(afB, bfB)  SGB_MIX()             // t3 || load t4
    LOADT(5, afB, bfB)
    MFMAT(afA, bfA)  SGB_MIX()             // t4 || load t5
    LOADT(6, afA, bfA)
    MFMAT(afB, bfB)  SGB_MIX()             // t5 || load t6
    LOADT(7, afB, bfB)
    MFMAT(afA, bfA)  SGB_MIX()             // t6 || load t7
    LOADT(8, afA, bfA)
    MFMAT(afB, bfB)  SGB_MIX()             // t7 || load t8
    MFMAT(afA, bfA)  SGB_MFMA()            // t8
  }

  // epilogue: D row = oc (= kb8*4+j), col = px (= l15)
  #pragma unroll
  for (int fm = 0; fm < 4; fm++) {
    #pragma unroll
    for (int j = 0; j < 4; j++) {
      int oc = oc0 + wm * 64 + fm * 16 + kb8 * 4 + j;
      float dm = dsc[b * OUT_C + oc];
      float* orow = out + ((size_t)b * OUT_C + oc) * NPX + h0 * 64;
      #pragma unroll
      for (int fn = 0; fn < 8; fn++) {
        int px = wn * 128 + fn * 16 + l15;
        orow[px] = acc[fm][fn][j] * dm;
      }
    }
  }
}

extern "C" void kernel_launch(void* const* d_in, const int* in_sizes, int n_in,
                              void* d_out, int out_size, void* d_ws, size_t ws_size,
                              hipStream_t stream) {
  const float* input  = (const float*)d_in[0];
  const float* style  = (const float*)d_in[1];
  const float* weight = (const float*)d_in[2];
  const float* mod_w  = (const float*)d_in[3];
  const float* mod_b  = (const float*)d_in[4];
  float* out = (float*)d_out;

  char* p = (char*)d_ws;
  float* s    = (float*)p;  p += (size_t)BATCH * IN_C * 4;       // 32 KB
  float* dsc  = (float*)p;  p += (size_t)BATCH * OUT_C * 4;      // 32 KB
  float* wsq  = (float*)p;  p += (size_t)OUT_C * IN_C * 4;       // 1 MB
  char*  wsw  = p;          p += (size_t)16 * 4 * WT_TILE_BYTES; // 4.5 MB
  __bf16* xm  = (__bf16*)p;                                      // 64 MB

  style_k<<<BATCH, 512, 0, stream>>>(style, mod_w, mod_b, s);
  wprep_k<<<1024, 256, 0, stream>>>(weight, wsq, wsw);
  demod_k<<<BATCH, 512, 0, stream>>>(s, wsq, dsc);
  modx_k<<<BATCH * 8 * 64, 256, 0, stream>>>(input, s, xm);
  conv_k<<<BATCH * 4 * 8, 512, 0, stream>>>(xm, wsw, dsc, out);
}